// Round 1
// baseline (11767.635 us; speedup 1.0000x reference)
//
#include <hip/hip_runtime.h>
#include <hip/hip_bf16.h>

#define BN_EPS 1e-5f

static inline int cdiv(long long a, long long b) { return (int)((a + b - 1) / b); }

// ---------------- degree kernels ----------------
__global__ void k_init_deg(float* __restrict__ deg, int N) {
    int i = blockIdx.x * blockDim.x + threadIdx.x;
    if (i < N) deg[i] = 1.0f;  // self-loop
}

__global__ void k_count_deg(const int* __restrict__ tgt, float* __restrict__ deg, int E) {
    int i = blockIdx.x * blockDim.x + threadIdx.x;
    if (i < E) atomicAdd(&deg[tgt[i]], 1.0f);
}

__global__ void k_rsqrt_deg(float* __restrict__ deg, int N) {
    int i = blockIdx.x * blockDim.x + threadIdx.x;
    if (i < N) deg[i] = rsqrtf(deg[i]);
}

// ---------------- GEMM: Y[N,M] = X[N,128] @ W[128,M] ----------------
// block: 256 threads, 32 rows x 128 cols per block; W tile staged in LDS.
__global__ __launch_bounds__(256) void k_gemm(const float* __restrict__ X,
                                              const float* __restrict__ W,
                                              float* __restrict__ Y, int N, int M) {
    __shared__ float wt[128 * 128];
    __shared__ float xt[32 * 128];
    const int t = threadIdx.x;
    const int rbase = blockIdx.x * 32;
    const int cbase = blockIdx.y * 128;

    for (int idx = t; idx < 128 * 128; idx += 256) {
        int k = idx >> 7, c = idx & 127;
        wt[idx] = W[k * M + cbase + c];
    }
    for (int idx = t; idx < 32 * 128; idx += 256) {
        int r = idx >> 7, k = idx & 127;
        int row = rbase + r;
        xt[idx] = (row < N) ? X[(long long)row * 128 + k] : 0.0f;
    }
    __syncthreads();

    const int r0 = t >> 7;    // 0..1
    const int c = t & 127;
    float acc[16];
#pragma unroll
    for (int i = 0; i < 16; i++) acc[i] = 0.0f;
    for (int k = 0; k < 128; k++) {
        float wv = wt[k * 128 + c];
#pragma unroll
        for (int i = 0; i < 16; i++) acc[i] += xt[(r0 + 2 * i) * 128 + k] * wv;
    }
#pragma unroll
    for (int i = 0; i < 16; i++) {
        int row = rbase + r0 + 2 * i;
        if (row < N) Y[(long long)row * M + cbase + c] = acc[i];
    }
}

// ---------------- self-loop + bias init: out = H*dis^2 + b ----------------
__global__ void k_self_bias(const float* __restrict__ H, const float* __restrict__ dis,
                            const float* __restrict__ bias, float* __restrict__ out,
                            long long total4, int M, int shift) {
    long long idx = (long long)blockIdx.x * blockDim.x + threadIdx.x;
    if (idx >= total4) return;
    int node = (int)(idx >> shift);
    int c4 = ((int)idx & ((M >> 2) - 1)) << 2;
    float d = dis[node];
    float d2 = d * d;
    const float4 h = *(const float4*)(H + (long long)node * M + c4);
    float4 o;
    o.x = h.x * d2 + bias[c4 + 0];
    o.y = h.y * d2 + bias[c4 + 1];
    o.z = h.z * d2 + bias[c4 + 2];
    o.w = h.w * d2 + bias[c4 + 3];
    *(float4*)(out + (long long)node * M + c4) = o;
}

// ---------------- edge scatter: out[tgt] += H[src] * dis[src]*dis[tgt] ----------------
__global__ void k_scatter(const float* __restrict__ H, const int* __restrict__ srcv,
                          const int* __restrict__ tgtv, const float* __restrict__ dis,
                          float* __restrict__ out, long long total, int M, int shift) {
    long long idx = (long long)blockIdx.x * blockDim.x + threadIdx.x;
    if (idx >= total) return;
    int e = (int)(idx >> shift);
    int c4 = ((int)idx & ((1 << shift) - 1)) << 2;
    int s = srcv[e], tg = tgtv[e];
    float nrm = dis[s] * dis[tg];
    const float4 h = *(const float4*)(H + (long long)s * M + c4);
    float* op = out + (long long)tg * M + c4;
    atomicAdd(op + 0, h.x * nrm);
    atomicAdd(op + 1, h.y * nrm);
    atomicAdd(op + 2, h.z * nrm);
    atomicAdd(op + 3, h.w * nrm);
}

// ---------------- BN stats: per-feature sum & sumsq (M=128) ----------------
__global__ __launch_bounds__(256) void k_bnstats(const float* __restrict__ X,
                                                 float* __restrict__ sums,
                                                 float* __restrict__ sumsq, int N) {
    __shared__ float s1[256], s2[256];
    const int t = threadIdx.x;
    const int c = t & 127, half = t >> 7;
    float a = 0.0f, b = 0.0f;
    for (long long row = (long long)blockIdx.x * 2 + half; row < N; row += (long long)gridDim.x * 2) {
        float v = X[row * 128 + c];
        a += v;
        b += v * v;
    }
    s1[t] = a;
    s2[t] = b;
    __syncthreads();
    if (half == 0) {
        a = s1[t] + s1[t + 128];
        b = s2[t] + s2[t + 128];
        atomicAdd(&sums[c], a);
        atomicAdd(&sumsq[c], b);
    }
}

// ---------------- BN apply + ReLU (in place, M=128) ----------------
__global__ void k_bn_relu(float* __restrict__ X, const float* __restrict__ sums,
                          const float* __restrict__ sumsq, const float* __restrict__ g,
                          const float* __restrict__ be, long long total4, float inv_n) {
    long long idx = (long long)blockIdx.x * blockDim.x + threadIdx.x;
    if (idx >= total4) return;
    int c4 = ((int)idx & 31) << 2;
    float4 v = *(float4*)(X + idx * 4);
    float o[4] = {v.x, v.y, v.z, v.w};
#pragma unroll
    for (int j = 0; j < 4; j++) {
        int c = c4 + j;
        float mean = sums[c] * inv_n;
        float var = sumsq[c] * inv_n - mean * mean;
        float sc = rsqrtf(var + BN_EPS) * g[c];
        o[j] = fmaxf((o[j] - mean) * sc + be[c], 0.0f);
    }
    v.x = o[0]; v.y = o[1]; v.z = o[2]; v.w = o[3];
    *(float4*)(X + idx * 4) = v;
}

// ---------------- pooling ----------------
__global__ void k_count_batch(const int* __restrict__ batch, float* __restrict__ cnt, int N) {
    int i = blockIdx.x * blockDim.x + threadIdx.x;
    if (i < N) atomicAdd(&cnt[batch[i]], 1.0f);
}

__global__ void k_pool(const float* __restrict__ H, const int* __restrict__ batch,
                       float* __restrict__ out, long long total) {
    long long idx = (long long)blockIdx.x * blockDim.x + threadIdx.x;
    if (idx >= total) return;
    int node = (int)(idx >> 6);
    int c4 = ((int)idx & 63) << 2;
    int b = batch[node];
    const float4 h = *(const float4*)(H + (long long)node * 256 + c4);
    float* op = out + (long long)b * 256 + c4;
    atomicAdd(op + 0, h.x);
    atomicAdd(op + 1, h.y);
    atomicAdd(op + 2, h.z);
    atomicAdd(op + 3, h.w);
}

__global__ void k_div(float* __restrict__ out, const float* __restrict__ cnt, int total) {
    int i = blockIdx.x * blockDim.x + threadIdx.x;
    if (i < total) out[i] /= fmaxf(cnt[i >> 8], 1.0f);
}

extern "C" void kernel_launch(void* const* d_in, const int* in_sizes, int n_in,
                              void* d_out, int out_size, void* d_ws, size_t ws_size,
                              hipStream_t stream) {
    const float* x     = (const float*)d_in[0];
    const int*   ei    = (const int*)d_in[1];
    const int*   batch = (const int*)d_in[2];
    const float* W1 = (const float*)d_in[3];
    const float* b1 = (const float*)d_in[4];
    const float* W2 = (const float*)d_in[5];
    const float* b2 = (const float*)d_in[6];
    const float* W3 = (const float*)d_in[7];
    const float* b3 = (const float*)d_in[8];
    const float* g1 = (const float*)d_in[9];
    const float* be1 = (const float*)d_in[10];
    const float* g2 = (const float*)d_in[11];
    const float* be2 = (const float*)d_in[12];
    float* out = (float*)d_out;

    const int N = in_sizes[2];
    const int E = in_sizes[1] / 2;
    const int G = out_size / 256;
    const int* src = ei;
    const int* tgt = ei + E;

    // workspace layout
    char* ws = (char*)d_ws;
    auto take = [&](size_t bytes) {
        char* p = ws;
        ws += (bytes + 255) & ~(size_t)255;
        return p;
    };
    float* bufA = (float*)take((size_t)N * 256 * 4);
    float* bufB = (float*)take((size_t)N * 256 * 4);
    float* dis  = (float*)take((size_t)N * 4);
    float* sums = (float*)take(512 * 4);  // sums[128] + sumsq[128]
    float* sumsq = sums + 128;
    float* cnt  = (float*)take((size_t)G * 4);

    const int B = 256;

    // degrees -> dis
    k_init_deg<<<cdiv(N, B), B, 0, stream>>>(dis, N);
    k_count_deg<<<cdiv(E, B), B, 0, stream>>>(tgt, dis, E);
    k_rsqrt_deg<<<cdiv(N, B), B, 0, stream>>>(dis, N);

    long long t4_128 = (long long)N * 32;      // N*128/4
    long long t4_256 = (long long)N * 64;      // N*256/4
    long long sc_128 = (long long)E * 32;
    long long sc_256 = (long long)E * 64;

    // ---- layer 1 ----
    k_gemm<<<dim3(cdiv(N, 32), 1), B, 0, stream>>>(x, W1, bufA, N, 128);
    k_self_bias<<<cdiv(t4_128, B), B, 0, stream>>>(bufA, dis, b1, bufB, t4_128, 128, 5);
    k_scatter<<<cdiv(sc_128, B), B, 0, stream>>>(bufA, src, tgt, dis, bufB, sc_128, 128, 5);
    hipMemsetAsync(sums, 0, 256 * 4, stream);
    k_bnstats<<<512, B, 0, stream>>>(bufB, sums, sumsq, N);
    k_bn_relu<<<cdiv(t4_128, B), B, 0, stream>>>(bufB, sums, sumsq, g1, be1, t4_128, 1.0f / N);

    // ---- layer 2 ----
    k_gemm<<<dim3(cdiv(N, 32), 1), B, 0, stream>>>(bufB, W2, bufA, N, 128);
    k_self_bias<<<cdiv(t4_128, B), B, 0, stream>>>(bufA, dis, b2, bufB, t4_128, 128, 5);
    k_scatter<<<cdiv(sc_128, B), B, 0, stream>>>(bufA, src, tgt, dis, bufB, sc_128, 128, 5);
    hipMemsetAsync(sums, 0, 256 * 4, stream);
    k_bnstats<<<512, B, 0, stream>>>(bufB, sums, sumsq, N);
    k_bn_relu<<<cdiv(t4_128, B), B, 0, stream>>>(bufB, sums, sumsq, g2, be2, t4_128, 1.0f / N);

    // ---- layer 3 (out width 256, no BN) ----
    k_gemm<<<dim3(cdiv(N, 32), 2), B, 0, stream>>>(bufB, W3, bufA, N, 256);
    k_self_bias<<<cdiv(t4_256, B), B, 0, stream>>>(bufA, dis, b3, bufB, t4_256, 256, 6);
    k_scatter<<<cdiv(sc_256, B), B, 0, stream>>>(bufA, src, tgt, dis, bufB, sc_256, 256, 6);

    // ---- global mean pool ----
    hipMemsetAsync(out, 0, (size_t)out_size * 4, stream);
    hipMemsetAsync(cnt, 0, (size_t)G * 4, stream);
    k_count_batch<<<cdiv(N, B), B, 0, stream>>>(batch, cnt, N);
    k_pool<<<cdiv(t4_256, B), B, 0, stream>>>(bufB, batch, out, t4_256);
    k_div<<<cdiv(out_size, B), B, 0, stream>>>(out, cnt, out_size);
}

// Round 2
// 1499.041 us; speedup vs baseline: 7.8501x; 7.8501x over previous
//
#include <hip/hip_runtime.h>
#include <hip/hip_bf16.h>

#define BN_EPS 1e-5f

static inline int cdiv(long long a, long long b) { return (int)((a + b - 1) / b); }

// ---------------- histogram: cnt[idx[i]] += 1 ----------------
__global__ void k_hist(const int* __restrict__ idx, int* __restrict__ cnt, int n) {
    int i = blockIdx.x * blockDim.x + threadIdx.x;
    if (i < n) atomicAdd(&cnt[idx[i]], 1);
}

// ---------------- single-block exclusive scan (n <= ~1M) ----------------
__global__ __launch_bounds__(1024) void k_scan(const int* __restrict__ cnt,
                                               int* __restrict__ off, int n) {
    __shared__ int part[1024];
    const int t = threadIdx.x;
    const int ipt = (n + 1023) >> 10;
    const int start = t * ipt;
    const int end = min(start + ipt, n);
    int s = 0;
    for (int i = start; i < end; i++) s += cnt[i];
    part[t] = s;
    __syncthreads();
    for (int d = 1; d < 1024; d <<= 1) {
        int v = (t >= d) ? part[t - d] : 0;
        __syncthreads();
        part[t] += v;
        __syncthreads();
    }
    int excl = (t == 0) ? 0 : part[t - 1];
    for (int i = start; i < end; i++) {
        off[i] = excl;
        excl += cnt[i];
    }
    if (t == 1023) off[n] = part[1023];
}

__global__ void k_copy_int(const int* __restrict__ a, int* __restrict__ b, int n) {
    int i = blockIdx.x * blockDim.x + threadIdx.x;
    if (i < n) b[i] = a[i];
}

// dis[i] = rsqrt(in_degree + 1)  (self loop)
__global__ void k_dis(const int* __restrict__ cnt, float* __restrict__ dis, int n) {
    int i = blockIdx.x * blockDim.x + threadIdx.x;
    if (i < n) dis[i] = rsqrtf((float)cnt[i] + 1.0f);
}

// sort edges by target into CSR slots
__global__ void k_fill(const int* __restrict__ src, const int* __restrict__ tgt,
                       int* __restrict__ cursor, int* __restrict__ esrc, int E) {
    int i = blockIdx.x * blockDim.x + threadIdx.x;
    if (i < E) {
        int t = tgt[i];
        int p = atomicAdd(&cursor[t], 1);
        esrc[p] = src[i];
    }
}

// ---------------- GEMM: Y[N,M] = X[N,128] @ W[128,M] ----------------
__global__ __launch_bounds__(256) void k_gemm(const float* __restrict__ X,
                                              const float* __restrict__ W,
                                              float* __restrict__ Y, int N, int M) {
    __shared__ float wt[128 * 128];
    __shared__ float xt[32 * 128];
    const int t = threadIdx.x;
    const int rbase = blockIdx.x * 32;
    const int cbase = blockIdx.y * 128;

    for (int idx = t; idx < 128 * 128; idx += 256) {
        int k = idx >> 7, c = idx & 127;
        wt[idx] = W[k * M + cbase + c];
    }
    for (int idx = t; idx < 32 * 128; idx += 256) {
        int r = idx >> 7, k = idx & 127;
        int row = rbase + r;
        xt[idx] = (row < N) ? X[(long long)row * 128 + k] : 0.0f;
    }
    __syncthreads();

    const int r0 = t >> 7;
    const int c = t & 127;
    float acc[16];
#pragma unroll
    for (int i = 0; i < 16; i++) acc[i] = 0.0f;
    for (int k = 0; k < 128; k++) {
        float wv = wt[k * 128 + c];
#pragma unroll
        for (int i = 0; i < 16; i++) acc[i] += xt[(r0 + 2 * i) * 128 + k] * wv;
    }
#pragma unroll
    for (int i = 0; i < 16; i++) {
        int row = rbase + r0 + 2 * i;
        if (row < N) Y[(long long)row * M + cbase + c] = acc[i];
    }
}

// ---------------- CSR aggregation (gather, no atomics) ----------------
// out[n] = sum_{e in csr(n)} H[esrc[e]] * dis[esrc[e]]*dis[n]  +  H[n]*dis[n]^2 + bias
template <int M>
__global__ __launch_bounds__(256) void k_aggr(const float* __restrict__ H,
                                              const int* __restrict__ esrc,
                                              const int* __restrict__ roff,
                                              const float* __restrict__ dis,
                                              const float* __restrict__ bias,
                                              float* __restrict__ out) {
    constexpr int LPR = M / 4;       // lanes per row (32 or 64)
    constexpr int GRP = 256 / LPR;   // edge-parallel groups (8 or 4)
    const int n = blockIdx.x;
    const int t = threadIdx.x;
    const int g = t / LPR;
    const int lane = t % LPR;
    const int c4 = lane * 4;
    const int rs = roff[n], re = roff[n + 1];
    const float dn = dis[n];

    float4 acc = make_float4(0.f, 0.f, 0.f, 0.f);
    for (int e = rs + g; e < re; e += GRP) {
        int s = esrc[e];
        float nrm = dis[s] * dn;
        const float4 h = *(const float4*)(H + (size_t)s * M + c4);
        acc.x += h.x * nrm;
        acc.y += h.y * nrm;
        acc.z += h.z * nrm;
        acc.w += h.w * nrm;
    }
    __shared__ float4 red[256];
    red[t] = acc;
    __syncthreads();
    if (g == 0) {
#pragma unroll
        for (int k = 1; k < GRP; k++) {
            float4 o = red[k * LPR + lane];
            acc.x += o.x; acc.y += o.y; acc.z += o.z; acc.w += o.w;
        }
        const float4 h = *(const float4*)(H + (size_t)n * M + c4);
        const float d2 = dn * dn;
        acc.x += h.x * d2 + bias[c4 + 0];
        acc.y += h.y * d2 + bias[c4 + 1];
        acc.z += h.z * d2 + bias[c4 + 2];
        acc.w += h.w * d2 + bias[c4 + 3];
        *(float4*)(out + (size_t)n * M + c4) = acc;
    }
}

// ---------------- BN stats: per-feature sum & sumsq (M=128) ----------------
__global__ __launch_bounds__(256) void k_bnstats(const float* __restrict__ X,
                                                 float* __restrict__ sums,
                                                 float* __restrict__ sumsq, int N) {
    __shared__ float s1[256], s2[256];
    const int t = threadIdx.x;
    const int c = t & 127, half = t >> 7;
    float a = 0.0f, b = 0.0f;
    for (long long row = (long long)blockIdx.x * 2 + half; row < N; row += (long long)gridDim.x * 2) {
        float v = X[row * 128 + c];
        a += v;
        b += v * v;
    }
    s1[t] = a;
    s2[t] = b;
    __syncthreads();
    if (half == 0) {
        a = s1[t] + s1[t + 128];
        b = s2[t] + s2[t + 128];
        atomicAdd(&sums[c], a);
        atomicAdd(&sumsq[c], b);
    }
}

// ---------------- BN apply + ReLU (in place, M=128) ----------------
__global__ void k_bn_relu(float* __restrict__ X, const float* __restrict__ sums,
                          const float* __restrict__ sumsq, const float* __restrict__ g,
                          const float* __restrict__ be, long long total4, float inv_n) {
    long long idx = (long long)blockIdx.x * blockDim.x + threadIdx.x;
    if (idx >= total4) return;
    int c4 = ((int)idx & 31) << 2;
    float4 v = *(float4*)(X + idx * 4);
    float o[4] = {v.x, v.y, v.z, v.w};
#pragma unroll
    for (int j = 0; j < 4; j++) {
        int c = c4 + j;
        float mean = sums[c] * inv_n;
        float var = sumsq[c] * inv_n - mean * mean;
        float sc = rsqrtf(var + BN_EPS) * g[c];
        o[j] = fmaxf((o[j] - mean) * sc + be[c], 0.0f);
    }
    v.x = o[0]; v.y = o[1]; v.z = o[2]; v.w = o[3];
    *(float4*)(X + idx * 4) = v;
}

// ---------------- segmented mean pool (batch is sorted) ----------------
__global__ __launch_bounds__(256) void k_pool_seg(const float* __restrict__ H,
                                                  const int* __restrict__ goff,
                                                  float* __restrict__ out) {
    const int gr = blockIdx.x;
    const int c = threadIdx.x;  // 256 cols
    const int s = goff[gr], e = goff[gr + 1];
    float acc = 0.0f;
    for (int i = s; i < e; i++) acc += H[(size_t)i * 256 + c];
    out[(size_t)gr * 256 + c] = acc / fmaxf((float)(e - s), 1.0f);
}

extern "C" void kernel_launch(void* const* d_in, const int* in_sizes, int n_in,
                              void* d_out, int out_size, void* d_ws, size_t ws_size,
                              hipStream_t stream) {
    const float* x     = (const float*)d_in[0];
    const int*   ei    = (const int*)d_in[1];
    const int*   batch = (const int*)d_in[2];
    const float* W1 = (const float*)d_in[3];
    const float* b1 = (const float*)d_in[4];
    const float* W2 = (const float*)d_in[5];
    const float* b2 = (const float*)d_in[6];
    const float* W3 = (const float*)d_in[7];
    const float* b3 = (const float*)d_in[8];
    const float* g1 = (const float*)d_in[9];
    const float* be1 = (const float*)d_in[10];
    const float* g2 = (const float*)d_in[11];
    const float* be2 = (const float*)d_in[12];
    float* out = (float*)d_out;

    const int N = in_sizes[2];
    const int E = in_sizes[1] / 2;
    const int G = out_size / 256;
    const int* src = ei;
    const int* tgt = ei + E;

    char* ws = (char*)d_ws;
    auto take = [&](size_t bytes) {
        char* p = ws;
        ws += (bytes + 255) & ~(size_t)255;
        return p;
    };
    float* bufA   = (float*)take((size_t)N * 256 * 4);
    float* bufB   = (float*)take((size_t)N * 256 * 4);
    float* dis    = (float*)take((size_t)N * 4);
    float* sums   = (float*)take(512 * 4);
    float* sumsq  = sums + 128;
    int*   ncnt   = (int*)take((size_t)N * 4);        // in-degree counts
    int*   roff   = (int*)take((size_t)(N + 1) * 4);  // CSR row offsets
    int*   cursor = (int*)take((size_t)N * 4);
    int*   esrc   = (int*)take((size_t)E * 4);        // edge srcs sorted by tgt
    int*   gcnt   = (int*)take((size_t)G * 4);
    int*   goff   = (int*)take((size_t)(G + 1) * 4);

    const int B = 256;

    // ---- CSR build (once, reused for 3 layers) ----
    hipMemsetAsync(ncnt, 0, (size_t)N * 4, stream);
    hipMemsetAsync(gcnt, 0, (size_t)G * 4, stream);
    k_hist<<<cdiv(E, B), B, 0, stream>>>(tgt, ncnt, E);
    k_hist<<<cdiv(N, B), B, 0, stream>>>(batch, gcnt, N);
    k_scan<<<1, 1024, 0, stream>>>(ncnt, roff, N);
    k_scan<<<1, 1024, 0, stream>>>(gcnt, goff, G);
    k_dis<<<cdiv(N, B), B, 0, stream>>>(ncnt, dis, N);
    k_copy_int<<<cdiv(N, B), B, 0, stream>>>(roff, cursor, N);
    k_fill<<<cdiv(E, B), B, 0, stream>>>(src, tgt, cursor, esrc, E);

    long long t4_128 = (long long)N * 32;

    // ---- layer 1 ----
    k_gemm<<<dim3(cdiv(N, 32), 1), B, 0, stream>>>(x, W1, bufA, N, 128);
    k_aggr<128><<<N, B, 0, stream>>>(bufA, esrc, roff, dis, b1, bufB);
    hipMemsetAsync(sums, 0, 256 * 4, stream);
    k_bnstats<<<512, B, 0, stream>>>(bufB, sums, sumsq, N);
    k_bn_relu<<<cdiv(t4_128, B), B, 0, stream>>>(bufB, sums, sumsq, g1, be1, t4_128, 1.0f / N);

    // ---- layer 2 ----
    k_gemm<<<dim3(cdiv(N, 32), 1), B, 0, stream>>>(bufB, W2, bufA, N, 128);
    k_aggr<128><<<N, B, 0, stream>>>(bufA, esrc, roff, dis, b2, bufB);
    hipMemsetAsync(sums, 0, 256 * 4, stream);
    k_bnstats<<<512, B, 0, stream>>>(bufB, sums, sumsq, N);
    k_bn_relu<<<cdiv(t4_128, B), B, 0, stream>>>(bufB, sums, sumsq, g2, be2, t4_128, 1.0f / N);

    // ---- layer 3 (width 256) ----
    k_gemm<<<dim3(cdiv(N, 32), 2), B, 0, stream>>>(bufB, W3, bufA, N, 256);
    k_aggr<256><<<N, B, 0, stream>>>(bufA, esrc, roff, dis, b3, bufB);

    // ---- global mean pool (segmented, batch sorted) ----
    k_pool_seg<<<G, B, 0, stream>>>(bufB, goff, out);
}

// Round 3
// 1260.033 us; speedup vs baseline: 9.3392x; 1.1897x over previous
//
#include <hip/hip_runtime.h>
#include <hip/hip_bf16.h>

#define BN_EPS 1e-5f

static inline int cdiv(long long a, long long b) { return (int)((a + b - 1) / b); }

__device__ __forceinline__ float bf2f(unsigned short u) {
    return __uint_as_float(((unsigned int)u) << 16);
}
__device__ __forceinline__ unsigned short f2bf(float f) {
    unsigned int b = __float_as_uint(f);
    b += 0x7FFFu + ((b >> 16) & 1u);  // RNE
    return (unsigned short)(b >> 16);
}

// ---------------- histogram ----------------
__global__ void k_hist(const int* __restrict__ idx, int* __restrict__ cnt, int n) {
    int i = blockIdx.x * blockDim.x + threadIdx.x;
    if (i < n) atomicAdd(&cnt[idx[i]], 1);
}

// ---------------- single-block exclusive scan ----------------
__global__ __launch_bounds__(1024) void k_scan(const int* __restrict__ cnt,
                                               int* __restrict__ off, int n) {
    __shared__ int part[1024];
    const int t = threadIdx.x;
    const int ipt = (n + 1023) >> 10;
    const int start = t * ipt;
    const int end = min(start + ipt, n);
    int s = 0;
    for (int i = start; i < end; i++) s += cnt[i];
    part[t] = s;
    __syncthreads();
    for (int d = 1; d < 1024; d <<= 1) {
        int v = (t >= d) ? part[t - d] : 0;
        __syncthreads();
        part[t] += v;
        __syncthreads();
    }
    int excl = (t == 0) ? 0 : part[t - 1];
    for (int i = start; i < end; i++) {
        off[i] = excl;
        excl += cnt[i];
    }
    if (t == 1023) off[n] = part[1023];
}

__global__ void k_copy_int(const int* __restrict__ a, int* __restrict__ b, int n) {
    int i = blockIdx.x * blockDim.x + threadIdx.x;
    if (i < n) b[i] = a[i];
}

__global__ void k_dis(const int* __restrict__ cnt, float* __restrict__ dis, int n) {
    int i = blockIdx.x * blockDim.x + threadIdx.x;
    if (i < n) dis[i] = rsqrtf((float)cnt[i] + 1.0f);
}

__global__ void k_fill(const int* __restrict__ src, const int* __restrict__ tgt,
                       int* __restrict__ cursor, int* __restrict__ esrc, int E) {
    int i = blockIdx.x * blockDim.x + threadIdx.x;
    if (i < E) {
        int t = tgt[i];
        int p = atomicAdd(&cursor[t], 1);
        esrc[p] = src[i];
    }
}

// ---------------- GEMM: Ybf16[N,M] = BN?(X)[N,128] @ W[128,M] ----------------
// 64x64 tile, 256 threads, each thread 4x4; LDS X transposed so inner loop is
// 2 x ds_read_b128 per 16 FMA.
template <int M, bool BN>
__global__ __launch_bounds__(256) void k_gemm2(const float* __restrict__ X,
                                               const float* __restrict__ W,
                                               unsigned short* __restrict__ Y, int N,
                                               const float* __restrict__ sums,
                                               const float* __restrict__ sumsq,
                                               const float* __restrict__ g,
                                               const float* __restrict__ be,
                                               float inv_n) {
    __shared__ float xt[128][64];  // [k][row]
    __shared__ float wt[128][64];  // [k][col]
    const int t = threadIdx.x;
    const int rbase = blockIdx.x * 64;
    const int cbase = blockIdx.y * 64;

    // stage X (transposed), optional BN+ReLU
    for (int it = 0; it < 8; it++) {
        int idx = t + it * 256;           // [0, 64*32)
        int k4 = idx >> 6;                // 0..31
        int r = idx & 63;
        int row = rbase + r;
        float4 v = make_float4(0.f, 0.f, 0.f, 0.f);
        if (row < N) v = *(const float4*)(X + (size_t)row * 128 + k4 * 4);
        if (BN) {
            float o[4] = {v.x, v.y, v.z, v.w};
#pragma unroll
            for (int j = 0; j < 4; j++) {
                int c = k4 * 4 + j;
                float mean = sums[c] * inv_n;
                float var = sumsq[c] * inv_n - mean * mean;
                float sc = rsqrtf(var + BN_EPS) * g[c];
                o[j] = fmaxf((o[j] - mean) * sc + be[c], 0.0f);
            }
            v.x = o[0]; v.y = o[1]; v.z = o[2]; v.w = o[3];
        }
        xt[k4 * 4 + 0][r] = v.x;
        xt[k4 * 4 + 1][r] = v.y;
        xt[k4 * 4 + 2][r] = v.z;
        xt[k4 * 4 + 3][r] = v.w;
    }
    // stage W
    for (int it = 0; it < 8; it++) {
        int idx = t + it * 256;           // [0, 128*16)
        int k = idx >> 4;
        int c4 = (idx & 15) * 4;
        *(float4*)&wt[k][c4] = *(const float4*)(W + (size_t)k * M + cbase + c4);
    }
    __syncthreads();

    const int r0 = (t >> 4) * 4;
    const int c0 = (t & 15) * 4;
    float acc[4][4];
#pragma unroll
    for (int i = 0; i < 4; i++)
#pragma unroll
        for (int j = 0; j < 4; j++) acc[i][j] = 0.0f;

#pragma unroll 4
    for (int k = 0; k < 128; k++) {
        float4 a = *(const float4*)&xt[k][r0];
        float4 b = *(const float4*)&wt[k][c0];
        const float av[4] = {a.x, a.y, a.z, a.w};
        const float bv[4] = {b.x, b.y, b.z, b.w};
#pragma unroll
        for (int i = 0; i < 4; i++)
#pragma unroll
            for (int j = 0; j < 4; j++) acc[i][j] += av[i] * bv[j];
    }

#pragma unroll
    for (int i = 0; i < 4; i++) {
        int row = rbase + r0 + i;
        if (row < N) {
            ushort4 o;
            o.x = f2bf(acc[i][0]);
            o.y = f2bf(acc[i][1]);
            o.z = f2bf(acc[i][2]);
            o.w = f2bf(acc[i][3]);
            *(ushort4*)(Y + (size_t)row * M + cbase + c0) = o;
        }
    }
}

// ---------------- CSR aggregation (gather, bf16 H, f32 accumulate) ----------------
template <int M>
__global__ __launch_bounds__(256) void k_aggr(const unsigned short* __restrict__ H,
                                              const int* __restrict__ esrc,
                                              const int* __restrict__ roff,
                                              const float* __restrict__ dis,
                                              const float* __restrict__ bias,
                                              float* __restrict__ out) {
    constexpr int LPR = M / 4;       // lanes per row (32 or 64)
    constexpr int GRP = 256 / LPR;   // edge-parallel groups (8 or 4)
    const int n = blockIdx.x;
    const int t = threadIdx.x;
    const int g = t / LPR;
    const int lane = t % LPR;
    const int c4 = lane * 4;
    const int rs = roff[n], re = roff[n + 1];
    const float dn = dis[n];

    float4 acc = make_float4(0.f, 0.f, 0.f, 0.f);
    for (int e = rs + g; e < re; e += GRP) {
        int s = esrc[e];
        float nrm = dis[s] * dn;
        ushort4 h = *(const ushort4*)(H + (size_t)s * M + c4);
        acc.x += bf2f(h.x) * nrm;
        acc.y += bf2f(h.y) * nrm;
        acc.z += bf2f(h.z) * nrm;
        acc.w += bf2f(h.w) * nrm;
    }
    __shared__ float4 red[256];
    red[t] = acc;
    __syncthreads();
    if (g == 0) {
#pragma unroll
        for (int k = 1; k < GRP; k++) {
            float4 o = red[k * LPR + lane];
            acc.x += o.x; acc.y += o.y; acc.z += o.z; acc.w += o.w;
        }
        ushort4 h = *(const ushort4*)(H + (size_t)n * M + c4);
        const float d2 = dn * dn;
        acc.x += bf2f(h.x) * d2 + bias[c4 + 0];
        acc.y += bf2f(h.y) * d2 + bias[c4 + 1];
        acc.z += bf2f(h.z) * d2 + bias[c4 + 2];
        acc.w += bf2f(h.w) * d2 + bias[c4 + 3];
        *(float4*)(out + (size_t)n * M + c4) = acc;
    }
}

// ---------------- BN stats: per-feature sum & sumsq (M=128) ----------------
__global__ __launch_bounds__(256) void k_bnstats(const float* __restrict__ X,
                                                 float* __restrict__ sums,
                                                 float* __restrict__ sumsq, int N) {
    __shared__ float s1[256], s2[256];
    const int t = threadIdx.x;
    const int c = t & 127, half = t >> 7;
    float a = 0.0f, b = 0.0f;
    for (long long row = (long long)blockIdx.x * 2 + half; row < N; row += (long long)gridDim.x * 2) {
        float v = X[row * 128 + c];
        a += v;
        b += v * v;
    }
    s1[t] = a;
    s2[t] = b;
    __syncthreads();
    if (half == 0) {
        a = s1[t] + s1[t + 128];
        b = s2[t] + s2[t + 128];
        atomicAdd(&sums[c], a);
        atomicAdd(&sumsq[c], b);
    }
}

// ---------------- segmented mean pool (batch sorted) ----------------
__global__ __launch_bounds__(256) void k_pool_seg(const float* __restrict__ H,
                                                  const int* __restrict__ goff,
                                                  float* __restrict__ out) {
    const int gr = blockIdx.x;
    const int c = threadIdx.x;
    const int s = goff[gr], e = goff[gr + 1];
    float acc = 0.0f;
    for (int i = s; i < e; i++) acc += H[(size_t)i * 256 + c];
    out[(size_t)gr * 256 + c] = acc / fmaxf((float)(e - s), 1.0f);
}

extern "C" void kernel_launch(void* const* d_in, const int* in_sizes, int n_in,
                              void* d_out, int out_size, void* d_ws, size_t ws_size,
                              hipStream_t stream) {
    const float* x     = (const float*)d_in[0];
    const int*   ei    = (const int*)d_in[1];
    const int*   batch = (const int*)d_in[2];
    const float* W1 = (const float*)d_in[3];
    const float* b1 = (const float*)d_in[4];
    const float* W2 = (const float*)d_in[5];
    const float* b2 = (const float*)d_in[6];
    const float* W3 = (const float*)d_in[7];
    const float* b3 = (const float*)d_in[8];
    const float* g1 = (const float*)d_in[9];
    const float* be1 = (const float*)d_in[10];
    const float* g2 = (const float*)d_in[11];
    const float* be2 = (const float*)d_in[12];
    float* out = (float*)d_out;

    const int N = in_sizes[2];
    const int E = in_sizes[1] / 2;
    const int G = out_size / 256;
    const int* src = ei;
    const int* tgt = ei + E;

    char* ws = (char*)d_ws;
    auto take = [&](size_t bytes) {
        char* p = ws;
        ws += (bytes + 255) & ~(size_t)255;
        return p;
    };
    float*          bufB   = (float*)take((size_t)N * 256 * 4);          // f32 agg outputs
    unsigned short* bufH   = (unsigned short*)take((size_t)N * 256 * 2); // bf16 GEMM outputs
    float*          dis    = (float*)take((size_t)N * 4);
    float*          sums   = (float*)take(512 * 4);
    float*          sumsq  = sums + 128;
    int*            ncnt   = (int*)take((size_t)N * 4);
    int*            roff   = (int*)take((size_t)(N + 1) * 4);
    int*            cursor = (int*)take((size_t)N * 4);
    int*            esrc   = (int*)take((size_t)E * 4);
    int*            gcnt   = (int*)take((size_t)G * 4);
    int*            goff   = (int*)take((size_t)(G + 1) * 4);

    const int B = 256;

    // ---- CSR build ----
    hipMemsetAsync(ncnt, 0, (size_t)N * 4, stream);
    hipMemsetAsync(gcnt, 0, (size_t)G * 4, stream);
    k_hist<<<cdiv(E, B), B, 0, stream>>>(tgt, ncnt, E);
    k_hist<<<cdiv(N, B), B, 0, stream>>>(batch, gcnt, N);
    k_scan<<<1, 1024, 0, stream>>>(ncnt, roff, N);
    k_scan<<<1, 1024, 0, stream>>>(gcnt, goff, G);
    k_dis<<<cdiv(N, B), B, 0, stream>>>(ncnt, dis, N);
    k_copy_int<<<cdiv(N, B), B, 0, stream>>>(roff, cursor, N);
    k_fill<<<cdiv(E, B), B, 0, stream>>>(src, tgt, cursor, esrc, E);

    // ---- layer 1 ----
    k_gemm2<128, false><<<dim3(cdiv(N, 64), 2), B, 0, stream>>>(x, W1, bufH, N,
                                                                nullptr, nullptr, nullptr, nullptr, 0.f);
    k_aggr<128><<<N, B, 0, stream>>>(bufH, esrc, roff, dis, b1, bufB);
    hipMemsetAsync(sums, 0, 256 * 4, stream);
    k_bnstats<<<512, B, 0, stream>>>(bufB, sums, sumsq, N);

    // ---- layer 2 (BN of layer-1 output fused into GEMM staging) ----
    k_gemm2<128, true><<<dim3(cdiv(N, 64), 2), B, 0, stream>>>(bufB, W2, bufH, N,
                                                               sums, sumsq, g1, be1, 1.0f / N);
    k_aggr<128><<<N, B, 0, stream>>>(bufH, esrc, roff, dis, b2, bufB);
    hipMemsetAsync(sums, 0, 256 * 4, stream);
    k_bnstats<<<512, B, 0, stream>>>(bufB, sums, sumsq, N);

    // ---- layer 3 (width 256) ----
    k_gemm2<256, true><<<dim3(cdiv(N, 64), 4), B, 0, stream>>>(bufB, W3, bufH, N,
                                                               sums, sumsq, g2, be2, 1.0f / N);
    k_aggr<256><<<N, B, 0, stream>>>(bufH, esrc, roff, dis, b3, bufB);

    // ---- global mean pool ----
    k_pool_seg<<<G, B, 0, stream>>>(bufB, goff, out);
}

// Round 4
// 977.600 us; speedup vs baseline: 12.0373x; 1.2889x over previous
//
#include <hip/hip_runtime.h>
#include <hip/hip_bf16.h>

#define BN_EPS 1e-5f

static inline int cdiv(long long a, long long b) { return (int)((a + b - 1) / b); }

__device__ __forceinline__ float bf2f(unsigned short u) {
    return __uint_as_float(((unsigned int)u) << 16);
}
__device__ __forceinline__ unsigned short f2bf(float f) {
    unsigned int b = __float_as_uint(f);
    b += 0x7FFFu + ((b >> 16) & 1u);  // RNE
    return (unsigned short)(b >> 16);
}

// ---------------- histogram ----------------
__global__ void k_hist(const int* __restrict__ idx, int* __restrict__ cnt, int n) {
    int i = blockIdx.x * blockDim.x + threadIdx.x;
    if (i < n) atomicAdd(&cnt[idx[i]], 1);
}

// ---------------- single-block exclusive scan ----------------
__global__ __launch_bounds__(1024) void k_scan(const int* __restrict__ cnt,
                                               int* __restrict__ off, int n) {
    __shared__ int part[1024];
    const int t = threadIdx.x;
    const int ipt = (n + 1023) >> 10;
    const int start = t * ipt;
    const int end = min(start + ipt, n);
    int s = 0;
    for (int i = start; i < end; i++) s += cnt[i];
    part[t] = s;
    __syncthreads();
    for (int d = 1; d < 1024; d <<= 1) {
        int v = (t >= d) ? part[t - d] : 0;
        __syncthreads();
        part[t] += v;
        __syncthreads();
    }
    int excl = (t == 0) ? 0 : part[t - 1];
    for (int i = start; i < end; i++) {
        off[i] = excl;
        excl += cnt[i];
    }
    if (t == 1023) off[n] = part[1023];
}

__global__ void k_copy_int(const int* __restrict__ a, int* __restrict__ b, int n) {
    int i = blockIdx.x * blockDim.x + threadIdx.x;
    if (i < n) b[i] = a[i];
}

__global__ void k_dis(const int* __restrict__ cnt, float* __restrict__ dis, int n) {
    int i = blockIdx.x * blockDim.x + threadIdx.x;
    if (i < n) dis[i] = rsqrtf((float)cnt[i] + 1.0f);
}

__global__ void k_fill(const int* __restrict__ src, const int* __restrict__ tgt,
                       int* __restrict__ cursor, int* __restrict__ esrc, int E) {
    int i = blockIdx.x * blockDim.x + threadIdx.x;
    if (i < E) {
        int t = tgt[i];
        int p = atomicAdd(&cursor[t], 1);
        esrc[p] = src[i];
    }
}

// ---------------- GEMM: Ybf16[N,M] = BN?(X)[N,128] @ W[128,M] ----------------
template <int M, bool BN>
__global__ __launch_bounds__(256) void k_gemm2(const float* __restrict__ X,
                                               const float* __restrict__ W,
                                               unsigned short* __restrict__ Y, int N,
                                               const float* __restrict__ sums,
                                               const float* __restrict__ sumsq,
                                               const float* __restrict__ g,
                                               const float* __restrict__ be,
                                               float inv_n) {
    __shared__ float xt[128][64];  // [k][row]
    __shared__ float wt[128][64];  // [k][col]
    const int t = threadIdx.x;
    const int rbase = blockIdx.x * 64;
    const int cbase = blockIdx.y * 64;

    for (int it = 0; it < 8; it++) {
        int idx = t + it * 256;
        int k4 = idx >> 6;
        int r = idx & 63;
        int row = rbase + r;
        float4 v = make_float4(0.f, 0.f, 0.f, 0.f);
        if (row < N) v = *(const float4*)(X + (size_t)row * 128 + k4 * 4);
        if (BN) {
            float o[4] = {v.x, v.y, v.z, v.w};
#pragma unroll
            for (int j = 0; j < 4; j++) {
                int c = k4 * 4 + j;
                float mean = sums[c] * inv_n;
                float var = sumsq[c] * inv_n - mean * mean;
                float sc = rsqrtf(var + BN_EPS) * g[c];
                o[j] = fmaxf((o[j] - mean) * sc + be[c], 0.0f);
            }
            v.x = o[0]; v.y = o[1]; v.z = o[2]; v.w = o[3];
        }
        xt[k4 * 4 + 0][r] = v.x;
        xt[k4 * 4 + 1][r] = v.y;
        xt[k4 * 4 + 2][r] = v.z;
        xt[k4 * 4 + 3][r] = v.w;
    }
    for (int it = 0; it < 8; it++) {
        int idx = t + it * 256;
        int k = idx >> 4;
        int c4 = (idx & 15) * 4;
        *(float4*)&wt[k][c4] = *(const float4*)(W + (size_t)k * M + cbase + c4);
    }
    __syncthreads();

    const int r0 = (t >> 4) * 4;
    const int c0 = (t & 15) * 4;
    float acc[4][4];
#pragma unroll
    for (int i = 0; i < 4; i++)
#pragma unroll
        for (int j = 0; j < 4; j++) acc[i][j] = 0.0f;

#pragma unroll 4
    for (int k = 0; k < 128; k++) {
        float4 a = *(const float4*)&xt[k][r0];
        float4 b = *(const float4*)&wt[k][c0];
        const float av[4] = {a.x, a.y, a.z, a.w};
        const float bv[4] = {b.x, b.y, b.z, b.w};
#pragma unroll
        for (int i = 0; i < 4; i++)
#pragma unroll
            for (int j = 0; j < 4; j++) acc[i][j] += av[i] * bv[j];
    }

#pragma unroll
    for (int i = 0; i < 4; i++) {
        int row = rbase + r0 + i;
        if (row < N) {
            ushort4 o;
            o.x = f2bf(acc[i][0]);
            o.y = f2bf(acc[i][1]);
            o.z = f2bf(acc[i][2]);
            o.w = f2bf(acc[i][3]);
            *(ushort4*)(Y + (size_t)row * M + cbase + c0) = o;
        }
    }
}

// ---------------- CSR aggregation: group-per-node, 4-edge MLP unroll ----------------
// group = M/4 lanes covering one row in ushort4 slices; grid-stride over nodes.
template <int M>
__global__ __launch_bounds__(256) void k_aggr2(const unsigned short* __restrict__ H,
                                               const int* __restrict__ esrc,
                                               const int* __restrict__ roff,
                                               const float* __restrict__ dis,
                                               const float* __restrict__ bias,
                                               float* __restrict__ out, int N) {
    constexpr int GSZ = M / 4;       // 32 (M=128) or 64 (M=256)
    constexpr int GPB = 256 / GSZ;   // groups per block: 8 or 4
    const int nGroups = gridDim.x * GPB;
    const int gid = blockIdx.x * GPB + threadIdx.x / GSZ;
    const int lane = threadIdx.x % GSZ;
    const int c4 = lane * 4;
    const float4 bv = *(const float4*)(bias + c4);

    for (int n = gid; n < N; n += nGroups) {
        const int rs = roff[n], re = roff[n + 1];
        const float dn = dis[n];
        float4 acc = make_float4(0.f, 0.f, 0.f, 0.f);

        int e = rs;
        for (; e + 4 <= re; e += 4) {
            const int s0 = esrc[e + 0];
            const int s1 = esrc[e + 1];
            const int s2 = esrc[e + 2];
            const int s3 = esrc[e + 3];
            const float w0 = dis[s0] * dn;
            const float w1 = dis[s1] * dn;
            const float w2 = dis[s2] * dn;
            const float w3 = dis[s3] * dn;
            const ushort4 h0 = *(const ushort4*)(H + (size_t)s0 * M + c4);
            const ushort4 h1 = *(const ushort4*)(H + (size_t)s1 * M + c4);
            const ushort4 h2 = *(const ushort4*)(H + (size_t)s2 * M + c4);
            const ushort4 h3 = *(const ushort4*)(H + (size_t)s3 * M + c4);
            acc.x += bf2f(h0.x) * w0 + bf2f(h1.x) * w1 + bf2f(h2.x) * w2 + bf2f(h3.x) * w3;
            acc.y += bf2f(h0.y) * w0 + bf2f(h1.y) * w1 + bf2f(h2.y) * w2 + bf2f(h3.y) * w3;
            acc.z += bf2f(h0.z) * w0 + bf2f(h1.z) * w1 + bf2f(h2.z) * w2 + bf2f(h3.z) * w3;
            acc.w += bf2f(h0.w) * w0 + bf2f(h1.w) * w1 + bf2f(h2.w) * w2 + bf2f(h3.w) * w3;
        }
        if (e < re) {  // predicated parallel tail (1..3 edges)
            const int rem = re - e;
            const int s0 = esrc[e];
            const int s1 = esrc[(rem > 1) ? e + 1 : e];
            const int s2 = esrc[(rem > 2) ? e + 2 : e];
            const float w0 = dis[s0] * dn;
            const float w1 = (rem > 1) ? dis[s1] * dn : 0.0f;
            const float w2 = (rem > 2) ? dis[s2] * dn : 0.0f;
            const ushort4 h0 = *(const ushort4*)(H + (size_t)s0 * M + c4);
            const ushort4 h1 = *(const ushort4*)(H + (size_t)s1 * M + c4);
            const ushort4 h2 = *(const ushort4*)(H + (size_t)s2 * M + c4);
            acc.x += bf2f(h0.x) * w0 + bf2f(h1.x) * w1 + bf2f(h2.x) * w2;
            acc.y += bf2f(h0.y) * w0 + bf2f(h1.y) * w1 + bf2f(h2.y) * w2;
            acc.z += bf2f(h0.z) * w0 + bf2f(h1.z) * w1 + bf2f(h2.z) * w2;
            acc.w += bf2f(h0.w) * w0 + bf2f(h1.w) * w1 + bf2f(h2.w) * w2;
        }

        const ushort4 hs = *(const ushort4*)(H + (size_t)n * M + c4);
        const float d2 = dn * dn;
        acc.x += bf2f(hs.x) * d2 + bv.x;
        acc.y += bf2f(hs.y) * d2 + bv.y;
        acc.z += bf2f(hs.z) * d2 + bv.z;
        acc.w += bf2f(hs.w) * d2 + bv.w;
        *(float4*)(out + (size_t)n * M + c4) = acc;
    }
}

// ---------------- BN stats: per-feature sum & sumsq (M=128) ----------------
__global__ __launch_bounds__(256) void k_bnstats(const float* __restrict__ X,
                                                 float* __restrict__ sums,
                                                 float* __restrict__ sumsq, int N) {
    __shared__ float s1[256], s2[256];
    const int t = threadIdx.x;
    const int c = t & 127, half = t >> 7;
    float a = 0.0f, b = 0.0f;
    for (long long row = (long long)blockIdx.x * 2 + half; row < N; row += (long long)gridDim.x * 2) {
        float v = X[row * 128 + c];
        a += v;
        b += v * v;
    }
    s1[t] = a;
    s2[t] = b;
    __syncthreads();
    if (half == 0) {
        a = s1[t] + s1[t + 128];
        b = s2[t] + s2[t + 128];
        atomicAdd(&sums[c], a);
        atomicAdd(&sumsq[c], b);
    }
}

// ---------------- segmented mean pool (batch sorted) ----------------
__global__ __launch_bounds__(256) void k_pool_seg(const float* __restrict__ H,
                                                  const int* __restrict__ goff,
                                                  float* __restrict__ out) {
    const int gr = blockIdx.x;
    const int c = threadIdx.x;
    const int s = goff[gr], e = goff[gr + 1];
    float acc = 0.0f;
    for (int i = s; i < e; i++) acc += H[(size_t)i * 256 + c];
    out[(size_t)gr * 256 + c] = acc / fmaxf((float)(e - s), 1.0f);
}

extern "C" void kernel_launch(void* const* d_in, const int* in_sizes, int n_in,
                              void* d_out, int out_size, void* d_ws, size_t ws_size,
                              hipStream_t stream) {
    const float* x     = (const float*)d_in[0];
    const int*   ei    = (const int*)d_in[1];
    const int*   batch = (const int*)d_in[2];
    const float* W1 = (const float*)d_in[3];
    const float* b1 = (const float*)d_in[4];
    const float* W2 = (const float*)d_in[5];
    const float* b2 = (const float*)d_in[6];
    const float* W3 = (const float*)d_in[7];
    const float* b3 = (const float*)d_in[8];
    const float* g1 = (const float*)d_in[9];
    const float* be1 = (const float*)d_in[10];
    const float* g2 = (const float*)d_in[11];
    const float* be2 = (const float*)d_in[12];
    float* out = (float*)d_out;

    const int N = in_sizes[2];
    const int E = in_sizes[1] / 2;
    const int G = out_size / 256;
    const int* src = ei;
    const int* tgt = ei + E;

    char* ws = (char*)d_ws;
    auto take = [&](size_t bytes) {
        char* p = ws;
        ws += (bytes + 255) & ~(size_t)255;
        return p;
    };
    float*          bufB   = (float*)take((size_t)N * 256 * 4);
    unsigned short* bufH   = (unsigned short*)take((size_t)N * 256 * 2);
    float*          dis    = (float*)take((size_t)N * 4);
    float*          sums   = (float*)take(512 * 4);
    float*          sumsq  = sums + 128;
    int*            ncnt   = (int*)take((size_t)N * 4);
    int*            roff   = (int*)take((size_t)(N + 1) * 4);
    int*            cursor = (int*)take((size_t)N * 4);
    int*            esrc   = (int*)take((size_t)E * 4);
    int*            gcnt   = (int*)take((size_t)G * 4);
    int*            goff   = (int*)take((size_t)(G + 1) * 4);

    const int B = 256;
    const int AGG_BLOCKS = 2048;

    // ---- CSR build ----
    hipMemsetAsync(ncnt, 0, (size_t)N * 4, stream);
    hipMemsetAsync(gcnt, 0, (size_t)G * 4, stream);
    k_hist<<<cdiv(E, B), B, 0, stream>>>(tgt, ncnt, E);
    k_hist<<<cdiv(N, B), B, 0, stream>>>(batch, gcnt, N);
    k_scan<<<1, 1024, 0, stream>>>(ncnt, roff, N);
    k_scan<<<1, 1024, 0, stream>>>(gcnt, goff, G);
    k_dis<<<cdiv(N, B), B, 0, stream>>>(ncnt, dis, N);
    k_copy_int<<<cdiv(N, B), B, 0, stream>>>(roff, cursor, N);
    k_fill<<<cdiv(E, B), B, 0, stream>>>(src, tgt, cursor, esrc, E);

    // ---- layer 1 ----
    k_gemm2<128, false><<<dim3(cdiv(N, 64), 2), B, 0, stream>>>(x, W1, bufH, N,
                                                                nullptr, nullptr, nullptr, nullptr, 0.f);
    k_aggr2<128><<<AGG_BLOCKS, B, 0, stream>>>(bufH, esrc, roff, dis, b1, bufB, N);
    hipMemsetAsync(sums, 0, 256 * 4, stream);
    k_bnstats<<<512, B, 0, stream>>>(bufB, sums, sumsq, N);

    // ---- layer 2 (BN fused into GEMM staging) ----
    k_gemm2<128, true><<<dim3(cdiv(N, 64), 2), B, 0, stream>>>(bufB, W2, bufH, N,
                                                               sums, sumsq, g1, be1, 1.0f / N);
    k_aggr2<128><<<AGG_BLOCKS, B, 0, stream>>>(bufH, esrc, roff, dis, b2, bufB, N);
    hipMemsetAsync(sums, 0, 256 * 4, stream);
    k_bnstats<<<512, B, 0, stream>>>(bufB, sums, sumsq, N);

    // ---- layer 3 (width 256) ----
    k_gemm2<256, true><<<dim3(cdiv(N, 64), 4), B, 0, stream>>>(bufB, W3, bufH, N,
                                                               sums, sumsq, g2, be2, 1.0f / N);
    k_aggr2<256><<<AGG_BLOCKS, B, 0, stream>>>(bufH, esrc, roff, dis, b3, bufB, N);

    // ---- global mean pool ----
    k_pool_seg<<<G, B, 0, stream>>>(bufB, goff, out);
}

// Round 5
// 659.863 us; speedup vs baseline: 17.8334x; 1.4815x over previous
//
#include <hip/hip_runtime.h>
#include <hip/hip_bf16.h>

#define BN_EPS 1e-5f
#define SCAN_CHUNK 2048  // 256 threads * 8 elems

static inline int cdiv(long long a, long long b) { return (int)((a + b - 1) / b); }

__device__ __forceinline__ float bf2f(unsigned short u) {
    return __uint_as_float(((unsigned int)u) << 16);
}
__device__ __forceinline__ unsigned short f2bf(float f) {
    unsigned int b = __float_as_uint(f);
    b += 0x7FFFu + ((b >> 16) & 1u);  // RNE
    return (unsigned short)(b >> 16);
}

// ---------------- histogram ----------------
__global__ void k_hist(const int* __restrict__ idx, int* __restrict__ cnt, int n) {
    int i = blockIdx.x * blockDim.x + threadIdx.x;
    if (i < n) atomicAdd(&cnt[idx[i]], 1);
}

// ---------------- hierarchical scan: pass 1 (block sums) ----------------
__global__ __launch_bounds__(256) void k_scan_blk(const int* __restrict__ cnt,
                                                  int* __restrict__ bsum, int n) {
    const int t = threadIdx.x;
    const int base = blockIdx.x * SCAN_CHUNK + t * 8;
    int s = 0;
    if (base + 8 <= n) {
        int4 a = *(const int4*)(cnt + base);
        int4 b = *(const int4*)(cnt + base + 4);
        s = a.x + a.y + a.z + a.w + b.x + b.y + b.z + b.w;
    } else {
#pragma unroll
        for (int j = 0; j < 8; j++) {
            int i = base + j;
            if (i < n) s += cnt[i];
        }
    }
    __shared__ int red[256];
    red[t] = s;
    __syncthreads();
    for (int d = 128; d > 0; d >>= 1) {
        if (t < d) red[t] += red[t + d];
        __syncthreads();
    }
    if (t == 0) bsum[blockIdx.x] = red[0];
}

// ---------------- pass 2: scan of block sums (nb <= 256), writes off[n]=total ----------------
__global__ __launch_bounds__(256) void k_scan_bsum(int* __restrict__ bsum,
                                                   int* __restrict__ off, int nb, int n) {
    const int t = threadIdx.x;
    __shared__ int sh[256];
    int v = (t < nb) ? bsum[t] : 0;
    sh[t] = v;
    __syncthreads();
    for (int d = 1; d < 256; d <<= 1) {
        int u = (t >= d) ? sh[t - d] : 0;
        __syncthreads();
        sh[t] += u;
        __syncthreads();
    }
    if (t < nb) bsum[t] = sh[t] - v;  // exclusive block offset
    if (t == 255) off[n] = sh[255];   // grand total
}

// ---------------- pass 3: write exclusive offsets (+ optional dis/cursor fold-in) ----------------
__global__ __launch_bounds__(256) void k_scan_out(const int* __restrict__ cnt,
                                                  const int* __restrict__ bsum,
                                                  int* __restrict__ off, int n,
                                                  float* __restrict__ dis,
                                                  int* __restrict__ cursor) {
    const int t = threadIdx.x;
    const int base = blockIdx.x * SCAN_CHUNK + t * 8;
    int c[8], loc[8];
    int s = 0;
#pragma unroll
    for (int j = 0; j < 8; j++) {
        int i = base + j;
        c[j] = (i < n) ? cnt[i] : 0;
        loc[j] = s;
        s += c[j];
    }
    __shared__ int sh[256];
    sh[t] = s;
    __syncthreads();
    for (int d = 1; d < 256; d <<= 1) {
        int u = (t >= d) ? sh[t - d] : 0;
        __syncthreads();
        sh[t] += u;
        __syncthreads();
    }
    const int texcl = sh[t] - s + bsum[blockIdx.x];
#pragma unroll
    for (int j = 0; j < 8; j++) {
        int i = base + j;
        if (i < n) {
            int o = texcl + loc[j];
            off[i] = o;
            if (cursor) cursor[i] = o;
            if (dis) dis[i] = rsqrtf((float)c[j] + 1.0f);
        }
    }
}

__global__ void k_fill(const int* __restrict__ src, const int* __restrict__ tgt,
                       int* __restrict__ cursor, int* __restrict__ esrc, int E) {
    int i = blockIdx.x * blockDim.x + threadIdx.x;
    if (i < E) {
        int t = tgt[i];
        int p = atomicAdd(&cursor[t], 1);
        esrc[p] = src[i];
    }
}

// ---------------- GEMM: Ybf16[N,M] = BN?(X)[N,128] @ W[128,M] ----------------
template <int M, bool BN>
__global__ __launch_bounds__(256) void k_gemm2(const float* __restrict__ X,
                                               const float* __restrict__ W,
                                               unsigned short* __restrict__ Y, int N,
                                               const float* __restrict__ sums,
                                               const float* __restrict__ sumsq,
                                               const float* __restrict__ g,
                                               const float* __restrict__ be,
                                               float inv_n) {
    __shared__ float xt[128][64];  // [k][row]
    __shared__ float wt[128][64];  // [k][col]
    const int t = threadIdx.x;
    const int rbase = blockIdx.x * 64;
    const int cbase = blockIdx.y * 64;

    for (int it = 0; it < 8; it++) {
        int idx = t + it * 256;
        int k4 = idx >> 6;
        int r = idx & 63;
        int row = rbase + r;
        float4 v = make_float4(0.f, 0.f, 0.f, 0.f);
        if (row < N) v = *(const float4*)(X + (size_t)row * 128 + k4 * 4);
        if (BN) {
            float o[4] = {v.x, v.y, v.z, v.w};
#pragma unroll
            for (int j = 0; j < 4; j++) {
                int c = k4 * 4 + j;
                float mean = sums[c] * inv_n;
                float var = sumsq[c] * inv_n - mean * mean;
                float sc = rsqrtf(var + BN_EPS) * g[c];
                o[j] = fmaxf((o[j] - mean) * sc + be[c], 0.0f);
            }
            v.x = o[0]; v.y = o[1]; v.z = o[2]; v.w = o[3];
        }
        xt[k4 * 4 + 0][r] = v.x;
        xt[k4 * 4 + 1][r] = v.y;
        xt[k4 * 4 + 2][r] = v.z;
        xt[k4 * 4 + 3][r] = v.w;
    }
    for (int it = 0; it < 8; it++) {
        int idx = t + it * 256;
        int k = idx >> 4;
        int c4 = (idx & 15) * 4;
        *(float4*)&wt[k][c4] = *(const float4*)(W + (size_t)k * M + cbase + c4);
    }
    __syncthreads();

    const int r0 = (t >> 4) * 4;
    const int c0 = (t & 15) * 4;
    float acc[4][4];
#pragma unroll
    for (int i = 0; i < 4; i++)
#pragma unroll
        for (int j = 0; j < 4; j++) acc[i][j] = 0.0f;

#pragma unroll 4
    for (int k = 0; k < 128; k++) {
        float4 a = *(const float4*)&xt[k][r0];
        float4 b = *(const float4*)&wt[k][c0];
        const float av[4] = {a.x, a.y, a.z, a.w};
        const float bv[4] = {b.x, b.y, b.z, b.w};
#pragma unroll
        for (int i = 0; i < 4; i++)
#pragma unroll
            for (int j = 0; j < 4; j++) acc[i][j] += av[i] * bv[j];
    }

#pragma unroll
    for (int i = 0; i < 4; i++) {
        int row = rbase + r0 + i;
        if (row < N) {
            ushort4 o;
            o.x = f2bf(acc[i][0]);
            o.y = f2bf(acc[i][1]);
            o.z = f2bf(acc[i][2]);
            o.w = f2bf(acc[i][3]);
            *(ushort4*)(Y + (size_t)row * M + cbase + c0) = o;
        }
    }
}

// ---------------- final GEMM: out[G,256] = P[G,128] @ W3 + b3 (f32, empty-graph guard) ----------------
__global__ __launch_bounds__(256) void k_gemm_final(const float* __restrict__ X,
                                                    const float* __restrict__ W,
                                                    const float* __restrict__ bias,
                                                    const int* __restrict__ goff,
                                                    float* __restrict__ out, int G) {
    __shared__ float xt[128][64];
    __shared__ float wt[128][64];
    const int t = threadIdx.x;
    const int rbase = blockIdx.x * 64;
    const int cbase = blockIdx.y * 64;

    for (int it = 0; it < 8; it++) {
        int idx = t + it * 256;
        int k4 = idx >> 6;
        int r = idx & 63;
        int row = rbase + r;
        float4 v = make_float4(0.f, 0.f, 0.f, 0.f);
        if (row < G) v = *(const float4*)(X + (size_t)row * 128 + k4 * 4);
        xt[k4 * 4 + 0][r] = v.x;
        xt[k4 * 4 + 1][r] = v.y;
        xt[k4 * 4 + 2][r] = v.z;
        xt[k4 * 4 + 3][r] = v.w;
    }
    for (int it = 0; it < 8; it++) {
        int idx = t + it * 256;
        int k = idx >> 4;
        int c4 = (idx & 15) * 4;
        *(float4*)&wt[k][c4] = *(const float4*)(W + (size_t)k * 256 + cbase + c4);
    }
    __syncthreads();

    const int r0 = (t >> 4) * 4;
    const int c0 = (t & 15) * 4;
    float acc[4][4];
#pragma unroll
    for (int i = 0; i < 4; i++)
#pragma unroll
        for (int j = 0; j < 4; j++) acc[i][j] = 0.0f;

#pragma unroll 4
    for (int k = 0; k < 128; k++) {
        float4 a = *(const float4*)&xt[k][r0];
        float4 b = *(const float4*)&wt[k][c0];
        const float av[4] = {a.x, a.y, a.z, a.w};
        const float bv[4] = {b.x, b.y, b.z, b.w};
#pragma unroll
        for (int i = 0; i < 4; i++)
#pragma unroll
            for (int j = 0; j < 4; j++) acc[i][j] += av[i] * bv[j];
    }

#pragma unroll
    for (int i = 0; i < 4; i++) {
        int row = rbase + r0 + i;
        if (row < G) {
            bool empty = (goff[row + 1] == goff[row]);
            float4 o;
            o.x = empty ? 0.f : acc[i][0] + bias[cbase + c0 + 0];
            o.y = empty ? 0.f : acc[i][1] + bias[cbase + c0 + 1];
            o.z = empty ? 0.f : acc[i][2] + bias[cbase + c0 + 2];
            o.w = empty ? 0.f : acc[i][3] + bias[cbase + c0 + 3];
            *(float4*)(out + (size_t)row * 256 + cbase + c0) = o;
        }
    }
}

// ---------------- CSR aggregation: group-per-node, 4-edge MLP unroll ----------------
template <int M>
__global__ __launch_bounds__(256) void k_aggr2(const unsigned short* __restrict__ H,
                                               const int* __restrict__ esrc,
                                               const int* __restrict__ roff,
                                               const float* __restrict__ dis,
                                               const float* __restrict__ bias,
                                               float* __restrict__ out, int N) {
    constexpr int GSZ = M / 4;
    constexpr int GPB = 256 / GSZ;
    const int nGroups = gridDim.x * GPB;
    const int gid = blockIdx.x * GPB + threadIdx.x / GSZ;
    const int lane = threadIdx.x % GSZ;
    const int c4 = lane * 4;
    const float4 bv = *(const float4*)(bias + c4);

    for (int n = gid; n < N; n += nGroups) {
        const int rs = roff[n], re = roff[n + 1];
        const float dn = dis[n];
        float4 acc = make_float4(0.f, 0.f, 0.f, 0.f);

        int e = rs;
        for (; e + 4 <= re; e += 4) {
            const int s0 = esrc[e + 0];
            const int s1 = esrc[e + 1];
            const int s2 = esrc[e + 2];
            const int s3 = esrc[e + 3];
            const float w0 = dis[s0] * dn;
            const float w1 = dis[s1] * dn;
            const float w2 = dis[s2] * dn;
            const float w3 = dis[s3] * dn;
            const ushort4 h0 = *(const ushort4*)(H + (size_t)s0 * M + c4);
            const ushort4 h1 = *(const ushort4*)(H + (size_t)s1 * M + c4);
            const ushort4 h2 = *(const ushort4*)(H + (size_t)s2 * M + c4);
            const ushort4 h3 = *(const ushort4*)(H + (size_t)s3 * M + c4);
            acc.x += bf2f(h0.x) * w0 + bf2f(h1.x) * w1 + bf2f(h2.x) * w2 + bf2f(h3.x) * w3;
            acc.y += bf2f(h0.y) * w0 + bf2f(h1.y) * w1 + bf2f(h2.y) * w2 + bf2f(h3.y) * w3;
            acc.z += bf2f(h0.z) * w0 + bf2f(h1.z) * w1 + bf2f(h2.z) * w2 + bf2f(h3.z) * w3;
            acc.w += bf2f(h0.w) * w0 + bf2f(h1.w) * w1 + bf2f(h2.w) * w2 + bf2f(h3.w) * w3;
        }
        if (e < re) {
            const int rem = re - e;
            const int s0 = esrc[e];
            const int s1 = esrc[(rem > 1) ? e + 1 : e];
            const int s2 = esrc[(rem > 2) ? e + 2 : e];
            const float w0 = dis[s0] * dn;
            const float w1 = (rem > 1) ? dis[s1] * dn : 0.0f;
            const float w2 = (rem > 2) ? dis[s2] * dn : 0.0f;
            const ushort4 h0 = *(const ushort4*)(H + (size_t)s0 * M + c4);
            const ushort4 h1 = *(const ushort4*)(H + (size_t)s1 * M + c4);
            const ushort4 h2 = *(const ushort4*)(H + (size_t)s2 * M + c4);
            acc.x += bf2f(h0.x) * w0 + bf2f(h1.x) * w1 + bf2f(h2.x) * w2;
            acc.y += bf2f(h0.y) * w0 + bf2f(h1.y) * w1 + bf2f(h2.y) * w2;
            acc.z += bf2f(h0.z) * w0 + bf2f(h1.z) * w1 + bf2f(h2.z) * w2;
            acc.w += bf2f(h0.w) * w0 + bf2f(h1.w) * w1 + bf2f(h2.w) * w2;
        }

        const ushort4 hs = *(const ushort4*)(H + (size_t)n * M + c4);
        const float d2 = dn * dn;
        acc.x += bf2f(hs.x) * d2 + bv.x;
        acc.y += bf2f(hs.y) * d2 + bv.y;
        acc.z += bf2f(hs.z) * d2 + bv.z;
        acc.w += bf2f(hs.w) * d2 + bv.w;
        *(float4*)(out + (size_t)n * M + c4) = acc;
    }
}

// ---------------- BN stats ----------------
__global__ __launch_bounds__(256) void k_bnstats(const float* __restrict__ X,
                                                 float* __restrict__ sums,
                                                 float* __restrict__ sumsq, int N) {
    __shared__ float s1[256], s2[256];
    const int t = threadIdx.x;
    const int c = t & 127, half = t >> 7;
    float a = 0.0f, b = 0.0f;
    for (long long row = (long long)blockIdx.x * 2 + half; row < N; row += (long long)gridDim.x * 2) {
        float v = X[row * 128 + c];
        a += v;
        b += v * v;
    }
    s1[t] = a;
    s2[t] = b;
    __syncthreads();
    if (half == 0) {
        a = s1[t] + s1[t + 128];
        b = s2[t] + s2[t + 128];
        atomicAdd(&sums[c], a);
        atomicAdd(&sumsq[c], b);
    }
}

// ---------------- BN+ReLU -> bf16 cast (layer-3 input) ----------------
__global__ void k_bncast(const float* __restrict__ X, const float* __restrict__ sums,
                         const float* __restrict__ sumsq, const float* __restrict__ g,
                         const float* __restrict__ be, unsigned short* __restrict__ Y,
                         long long total4, float inv_n) {
    long long idx = (long long)blockIdx.x * blockDim.x + threadIdx.x;
    if (idx >= total4) return;
    int c4 = ((int)idx & 31) << 2;
    float4 v = *(const float4*)(X + idx * 4);
    float o[4] = {v.x, v.y, v.z, v.w};
    ushort4 r;
    unsigned short* rp = &r.x;
#pragma unroll
    for (int j = 0; j < 4; j++) {
        int c = c4 + j;
        float mean = sums[c] * inv_n;
        float var = sumsq[c] * inv_n - mean * mean;
        float sc = rsqrtf(var + BN_EPS) * g[c];
        rp[j] = f2bf(fmaxf((o[j] - mean) * sc + be[c], 0.0f));
    }
    *(ushort4*)(Y + idx * 4) = r;
}

// ---------------- segmented mean pool (batch sorted) ----------------
template <int M>
__global__ void k_pool_seg(const float* __restrict__ H, const int* __restrict__ goff,
                           float* __restrict__ out) {
    const int gr = blockIdx.x;
    const int c = threadIdx.x;  // M threads
    const int s = goff[gr], e = goff[gr + 1];
    float acc = 0.0f;
    for (int i = s; i < e; i++) acc += H[(size_t)i * M + c];
    out[(size_t)gr * M + c] = acc / fmaxf((float)(e - s), 1.0f);
}

extern "C" void kernel_launch(void* const* d_in, const int* in_sizes, int n_in,
                              void* d_out, int out_size, void* d_ws, size_t ws_size,
                              hipStream_t stream) {
    const float* x     = (const float*)d_in[0];
    const int*   ei    = (const int*)d_in[1];
    const int*   batch = (const int*)d_in[2];
    const float* W1 = (const float*)d_in[3];
    const float* b1 = (const float*)d_in[4];
    const float* W2 = (const float*)d_in[5];
    const float* b2 = (const float*)d_in[6];
    const float* W3 = (const float*)d_in[7];
    const float* b3 = (const float*)d_in[8];
    const float* g1 = (const float*)d_in[9];
    const float* be1 = (const float*)d_in[10];
    const float* g2 = (const float*)d_in[11];
    const float* be2 = (const float*)d_in[12];
    float* out = (float*)d_out;

    const int N = in_sizes[2];
    const int E = in_sizes[1] / 2;
    const int G = out_size / 256;
    const int* src = ei;
    const int* tgt = ei + E;

    char* ws = (char*)d_ws;
    auto take = [&](size_t bytes) {
        char* p = ws;
        ws += (bytes + 255) & ~(size_t)255;
        return p;
    };
    float*          bufB   = (float*)take((size_t)N * 256 * 4);
    unsigned short* bufH   = (unsigned short*)take((size_t)N * 256 * 2);
    float*          P      = (float*)take((size_t)G * 128 * 4);
    float*          dis    = (float*)take((size_t)N * 4);
    float*          sums   = (float*)take(512 * 4);
    float*          sumsq  = sums + 128;
    float*          zbias  = (float*)take(128 * 4);
    int*            ncnt   = (int*)take((size_t)N * 4);
    int*            roff   = (int*)take((size_t)(N + 1) * 4);
    int*            cursor = (int*)take((size_t)N * 4);
    int*            esrc   = (int*)take((size_t)E * 4);
    int*            gcnt   = (int*)take((size_t)G * 4);
    int*            goff   = (int*)take((size_t)(G + 1) * 4);
    int*            bsumN  = (int*)take(256 * 4);
    int*            bsumG  = (int*)take(256 * 4);

    const int B = 256;
    const int AGG_BLOCKS = 2048;
    const int nbN = cdiv(N, SCAN_CHUNK);
    const int nbG = cdiv(G, SCAN_CHUNK);

    // ---- CSR build ----
    hipMemsetAsync(ncnt, 0, (size_t)N * 4, stream);
    hipMemsetAsync(gcnt, 0, (size_t)G * 4, stream);
    hipMemsetAsync(zbias, 0, 128 * 4, stream);
    k_hist<<<cdiv(E, B), B, 0, stream>>>(tgt, ncnt, E);
    k_hist<<<cdiv(N, B), B, 0, stream>>>(batch, gcnt, N);
    k_scan_blk<<<nbN, B, 0, stream>>>(ncnt, bsumN, N);
    k_scan_bsum<<<1, B, 0, stream>>>(bsumN, roff, nbN, N);
    k_scan_out<<<nbN, B, 0, stream>>>(ncnt, bsumN, roff, N, dis, cursor);
    k_scan_blk<<<nbG, B, 0, stream>>>(gcnt, bsumG, G);
    k_scan_bsum<<<1, B, 0, stream>>>(bsumG, goff, nbG, G);
    k_scan_out<<<nbG, B, 0, stream>>>(gcnt, bsumG, goff, G, nullptr, nullptr);
    k_fill<<<cdiv(E, B), B, 0, stream>>>(src, tgt, cursor, esrc, E);

    long long t4_128 = (long long)N * 32;

    // ---- layer 1 ----
    k_gemm2<128, false><<<dim3(cdiv(N, 64), 2), B, 0, stream>>>(x, W1, bufH, N,
                                                                nullptr, nullptr, nullptr, nullptr, 0.f);
    k_aggr2<128><<<AGG_BLOCKS, B, 0, stream>>>(bufH, esrc, roff, dis, b1, bufB, N);
    hipMemsetAsync(sums, 0, 256 * 4, stream);
    k_bnstats<<<512, B, 0, stream>>>(bufB, sums, sumsq, N);

    // ---- layer 2 (BN1 fused into GEMM staging) ----
    k_gemm2<128, true><<<dim3(cdiv(N, 64), 2), B, 0, stream>>>(bufB, W2, bufH, N,
                                                               sums, sumsq, g1, be1, 1.0f / N);
    k_aggr2<128><<<AGG_BLOCKS, B, 0, stream>>>(bufH, esrc, roff, dis, b2, bufB, N);
    hipMemsetAsync(sums, 0, 256 * 4, stream);
    k_bnstats<<<512, B, 0, stream>>>(bufB, sums, sumsq, N);

    // ---- layer 3: BN2+ReLU cast -> aggregate in 128-dim -> pool -> small GEMM ----
    k_bncast<<<cdiv(t4_128, B), B, 0, stream>>>(bufB, sums, sumsq, g2, be2, bufH,
                                                t4_128, 1.0f / N);
    k_aggr2<128><<<AGG_BLOCKS, B, 0, stream>>>(bufH, esrc, roff, dis, zbias, bufB, N);
    k_pool_seg<128><<<G, 128, 0, stream>>>(bufB, goff, P);
    k_gemm_final<<<dim3(cdiv(G, 64), 4), B, 0, stream>>>(P, W3, b3, goff, out, G);
}